// Round 15
// baseline (414.414 us; speedup 1.0000x reference)
//
#include <hip/hip_runtime.h>
#include <cstddef>

#define BB 8
#define NN 1024
#define KK 20
#define CCAT 169
#define NT 32   // n-tiles of 32 in final fused GEMM
#define WTLD 384  // padded row length of transposed Wf4

// ---------------- neg dist, full grid, F-templated, double-buffered ---------
// (layers 2-4; layer 1 uses the fused knn3 kernel below)
template <int F>
__global__ __launch_bounds__(256) void dist_tile_kernel(
    const float* __restrict__ src, int bs, float* __restrict__ dist) {
  __shared__ float As[2][8][128];
  __shared__ float Bs[2][8][128];
  int b = blockIdx.z;
  int n0 = blockIdx.y * 128;
  int m0 = blockIdx.x * 128;
  int t = threadIdx.x;
  int tx = t & 15, ty = t >> 4;
  const float* p = src + (size_t)b * bs;

  float acc[8][8];
  float xn[8], xm[8];
#pragma unroll
  for (int i = 0; i < 8; ++i) {
    xn[i] = 0.f;
    xm[i] = 0.f;
#pragma unroll
    for (int j = 0; j < 8; ++j) acc[i][j] = 0.f;
  }

  int fr = t >> 5;
  int cc = (t & 31) << 2;
  constexpr int T = (F + 7) / 8;

  float4 av = {0.f, 0.f, 0.f, 0.f}, bv = {0.f, 0.f, 0.f, 0.f};
  if (fr < F) {  // tile 0
    av = *(const float4*)(p + (size_t)fr * NN + n0 + cc);
    bv = *(const float4*)(p + (size_t)fr * NN + m0 + cc);
  }
  *(float4*)&As[0][fr][cc] = av;
  *(float4*)&Bs[0][fr][cc] = bv;

#pragma unroll 1
  for (int k = 0; k < T; ++k) {
    __syncthreads();  // tile k staged; buf^1 consumers (tile k-1) done
    if (k + 1 < T) {
      int f = (k + 1) * 8 + fr;
      av = make_float4(0.f, 0.f, 0.f, 0.f);
      bv = make_float4(0.f, 0.f, 0.f, 0.f);
      if (f < F) {
        av = *(const float4*)(p + (size_t)f * NN + n0 + cc);
        bv = *(const float4*)(p + (size_t)f * NN + m0 + cc);
      }
    }
    const float(*A)[128] = As[k & 1];
    const float(*B)[128] = Bs[k & 1];
#pragma unroll
    for (int f2 = 0; f2 < 8; ++f2) {
      float4 al = *(const float4*)&A[f2][ty << 2];
      float4 ah = *(const float4*)&A[f2][64 + (ty << 2)];
      float4 bl = *(const float4*)&B[f2][tx << 2];
      float4 bh = *(const float4*)&B[f2][64 + (tx << 2)];
      float a[8] = {al.x, al.y, al.z, al.w, ah.x, ah.y, ah.z, ah.w};
      float bb[8] = {bl.x, bl.y, bl.z, bl.w, bh.x, bh.y, bh.z, bh.w};
#pragma unroll
      for (int i = 0; i < 8; ++i) xn[i] += a[i] * a[i];
#pragma unroll
      for (int j = 0; j < 8; ++j) xm[j] += bb[j] * bb[j];
#pragma unroll
      for (int i = 0; i < 8; ++i)
#pragma unroll
        for (int j = 0; j < 8; ++j) acc[i][j] += a[i] * bb[j];
    }
    if (k + 1 < T) {
      *(float4*)&As[(k + 1) & 1][fr][cc] = av;  // vmcnt wait lands HERE
      *(float4*)&Bs[(k + 1) & 1][fr][cc] = bv;
    }
  }

#pragma unroll
  for (int i = 0; i < 8; ++i)
#pragma unroll
    for (int j = 0; j < 8; ++j) acc[i][j] = 2.f * acc[i][j] - xn[i] - xm[j];

#pragma unroll
  for (int i = 0; i < 8; ++i) {
    int n = n0 + ((i < 4) ? ((ty << 2) + i) : (64 + (ty << 2) + i - 4));
    float* dr = dist + (((size_t)b * NN + n) << 10);
    *(float4*)(dr + m0 + (tx << 2)) =
        make_float4(acc[i][0], acc[i][1], acc[i][2], acc[i][3]);
    *(float4*)(dr + m0 + 64 + (tx << 2)) =
        make_float4(acc[i][4], acc[i][5], acc[i][6], acc[i][7]);
  }
}

// ---------------- shared top-k core: sort 16 keys, LDS queue, tournament ----
__device__ __forceinline__ void topk_core(
    unsigned long long key[16], unsigned long long (*q)[64], int lane,
    int* out) {
  // bitonic sort, descending (compile-time indices -> stays in VGPRs)
#pragma unroll
  for (int size = 2; size <= 16; size <<= 1) {
#pragma unroll
    for (int stride = size >> 1; stride > 0; stride >>= 1) {
#pragma unroll
      for (int i = 0; i < 16; ++i) {
        int j = i ^ stride;
        if (j > i) {
          unsigned long long a = key[i], c = key[j];
          bool desc = ((i & size) == 0);
          bool sw = desc ? (a < c) : (a > c);
          key[i] = sw ? c : a;
          key[j] = sw ? a : c;
        }
      }
    }
  }

  // spill sorted tail (slots 1..15) + sentinel; head stays in register
#pragma unroll
  for (int s = 1; s < 16; ++s) q[s - 1][lane] = key[s];
  q[15][lane] = 0ull;  // sentinel: below every real key, can't tie

  unsigned long long head = key[0];
  int ptr = 0;
  for (int r = 0; r < KK; ++r) {
    unsigned hv = (unsigned)(head >> 32);
    unsigned v = hv;
#pragma unroll
    for (int off = 32; off > 0; off >>= 1) {
      unsigned o = __shfl_xor(v, off, 64);
      v = (o > v) ? o : v;
    }
    unsigned long long tie = __ballot(hv == v);
    unsigned il;
    if (tie & (tie - 1)) {  // >=2 lanes tie in value: reduce low word
      unsigned c = (hv == v) ? (unsigned)head : 0u;
#pragma unroll
      for (int off = 32; off > 0; off >>= 1) {
        unsigned o = __shfl_xor(c, off, 64);
        c = (o > c) ? o : c;
      }
      il = c;
    } else {
      int wl = __builtin_ctzll(tie);
      il = __shfl((unsigned)head, wl, 64);
    }
    if (lane == 0) out[r] = (NN - 1) - (int)il;
    if (hv == v && (unsigned)head == il) {  // unique winner pops from LDS
      head = q[ptr][lane];
      ++ptr;
    }
  }
}

__device__ __forceinline__ unsigned long long mk_key(float val, int m) {
  unsigned u = __float_as_uint(val);
  u = (u & 0x80000000u) ? ~u : (u | 0x80000000u);
  return ((unsigned long long)u << 32) | (unsigned)(NN - 1 - m);
}

// ---------------- top-k from the dist matrix (layers 2-4) ----------------
__global__ __launch_bounds__(256) void topk_kernel(
    const float* __restrict__ dist, int* __restrict__ idx_out) {
  __shared__ unsigned long long q[4][16][64];  // 32 KB
  int wave = threadIdx.x >> 6;
  int lane = threadIdx.x & 63;
  int row = blockIdx.x * 4 + wave;
  const float* d = dist + ((size_t)row << 10);

  unsigned long long key[16];
  {
    const float4* dp = (const float4*)(d + (lane << 4));
#pragma unroll
    for (int qd = 0; qd < 4; ++qd) {
      float4 v4 = dp[qd];
      float vv[4] = {v4.x, v4.y, v4.z, v4.w};
#pragma unroll
      for (int e = 0; e < 4; ++e)
        key[(qd << 2) + e] = mk_key(vv[e], (lane << 4) + (qd << 2) + e);
    }
  }
  topk_core(key, q[wave], lane, idx_out + row * KK);
}

// ---------------- fused dist+topk for layer 1 (F=3): x fits in LDS ---------
__global__ __launch_bounds__(256) void knn3_kernel(
    const float* __restrict__ src, int* __restrict__ idx_out) {
  __shared__ float xl[3 * NN];                 // 12 KB
  __shared__ unsigned long long q[4][16][64];  // 32 KB
  int b = blockIdx.y;
  int t = threadIdx.x;
  int wave = t >> 6;
  int lane = t & 63;
  int n = blockIdx.x * 4 + wave;  // row within batch
  const float* sb = src + (size_t)b * 3 * NN;

#pragma unroll
  for (int r = 0; r < 3; ++r)
    ((float4*)xl)[t + 256 * r] = ((const float4*)sb)[t + 256 * r];
  __syncthreads();

  float xn0 = xl[n], xn1 = xl[NN + n], xn2 = xl[2 * NN + n];
  float xnn = xn0 * xn0 + xn1 * xn1 + xn2 * xn2;

  unsigned long long key[16];
#pragma unroll
  for (int s = 0; s < 16; ++s) {
    int m = lane + (s << 6);
    float xm0 = xl[m], xm1 = xl[NN + m], xm2 = xl[2 * NN + m];
    float dot = xn0 * xm0 + xn1 * xm1 + xn2 * xm2;
    float xmn = xm0 * xm0 + xm1 * xm1 + xm2 * xm2;
    key[s] = mk_key(2.f * dot - xnn - xmn, m);
  }
  topk_core(key, q[wave], lane, idx_out + ((size_t)b * NN + n) * KK);
}

// ---------------- fused transform + edge combine + mean over k --------------
template <int DD>
__global__ __launch_bounds__(256) void edge_fused_kernel(
    const float* __restrict__ src, int bs, int Co, int nsplit,
    const float* __restrict__ Wf, const float* __restrict__ Wd,
    const int* __restrict__ idx, int ooff, float* __restrict__ xcat) {
  __shared__ float4 UA[NN];   // 16 KB
  __shared__ float2 UB2[NN];  // 8 KB
  __shared__ float4 VA[NN];   // 16 KB
  __shared__ float2 VB2[NN];  // 8 KB
  __shared__ float4 Wlds[48];
  int bo = blockIdx.x;
  int b = bo / Co, o = bo % Co;
  int t = threadIdx.x;

  if (t < DD) {
    float wfa = Wf[o * 2 * DD + t];
    float wfb = Wf[o * 2 * DD + DD + t] - wfa;
    float wda = Wd[o * 2 * DD + t];
    float wdb = Wd[o * 2 * DD + DD + t] - wda;
    Wlds[t] = make_float4(wfa, wfb, wda, wdb);
  }
  __syncthreads();

  const float* sb = src + (size_t)b * bs;
  {
    int c0 = t << 2;
    float uf[3][4], vf[3][4], ud[3][4], vd[3][4];
#pragma unroll
    for (int r = 0; r < 3; ++r)
#pragma unroll
      for (int e = 0; e < 4; ++e) {
        uf[r][e] = 0.f; vf[r][e] = 0.f; ud[r][e] = 0.f; vd[r][e] = 0.f;
      }
#pragma unroll 2
    for (int i = 0; i < DD; ++i) {
      const float* row = sb + (size_t)i * 3 * NN + c0;
      float4 s0 = *(const float4*)(row);
      float4 s1 = *(const float4*)(row + 1024);
      float4 s2 = *(const float4*)(row + 2048);
      float se[3][4] = {{s0.x, s0.y, s0.z, s0.w},
                        {s1.x, s1.y, s1.z, s1.w},
                        {s2.x, s2.y, s2.z, s2.w}};
      float4 w = Wlds[i];
#pragma unroll
      for (int r = 0; r < 3; ++r)
#pragma unroll
        for (int e = 0; e < 4; ++e) {
          uf[r][e] += w.x * se[r][e];
          vf[r][e] += w.y * se[r][e];
          ud[r][e] += w.z * se[r][e];
          vd[r][e] += w.w * se[r][e];
        }
    }
#pragma unroll
    for (int e = 0; e < 4; ++e) {
      int n = (t << 2) + e;
      UA[n] = make_float4(uf[0][e], ud[0][e], uf[1][e], ud[1][e]);
      UB2[n] = make_float2(uf[2][e], ud[2][e]);
      VA[n] = make_float4(vf[0][e], vd[0][e], vf[1][e], vd[1][e]);
      VB2[n] = make_float2(vf[2][e], vd[2][e]);
    }
  }
  __syncthreads();

  const float inv_k = 1.f / KK;
  int cnt = NN / nsplit;
  int nbase = blockIdx.y * cnt;
  for (int n = nbase + t; n < nbase + cnt; n += 256) {
    float4 va = VA[n];
    float2 vb = VB2[n];
    const int4* ip = (const int4*)(idx + (b * NN + n) * KK);
    float a0 = 0.f, a1 = 0.f, a2 = 0.f;
#pragma unroll
    for (int qq = 0; qq < 5; ++qq) {
      int4 iv = ip[qq];
      int nbs[4] = {iv.x, iv.y, iv.z, iv.w};
#pragma unroll
      for (int jj = 0; jj < 4; ++jj) {
        int nb = nbs[jj];
        float4 ua = UA[nb];
        float2 ub = UB2[nb];
        float pf0 = ua.x + va.x, pd0 = ua.y + va.y;
        float pf1 = ua.z + va.z, pd1 = ua.w + va.w;
        float pf2 = ub.x + vb.x, pd2 = ub.y + vb.y;
        float dot = pf0 * pd0 + pf1 * pd1 + pf2 * pd2;
        float dsq = pd0 * pd0 + pd1 * pd1 + pd2 * pd2;
        float g = (dot >= 0.f) ? 0.f : 0.8f * dot / (dsq + 1e-6f);
        a0 += pf0 - g * pd0;
        a1 += pf1 - g * pd1;
        a2 += pf2 - g * pd2;
      }
    }
    size_t ob = (size_t)b * CCAT * 3 * NN + (size_t)(ooff + o) * 3 * NN + n;
    xcat[ob] = a0 * inv_k;
    xcat[ob + NN] = a1 * inv_k;
    xcat[ob + 2 * NN] = a2 * inv_k;
  }
}

// ---------------- prep: transpose Wf4 -> Wt[176][384] (zero-padded), zero pad
__global__ __launch_bounds__(256) void prep_kernel(
    const float* __restrict__ Wf4, float* __restrict__ Wt,
    float* __restrict__ zpad) {
  int o = blockIdx.x * 256 + threadIdx.x;  // 0..511
  int f = blockIdx.y;                      // 0..175
  if (o < WTLD)
    Wt[(size_t)f * WTLD + o] = (f < CCAT && o < 341) ? Wf4[o * CCAT + f] : 0.f;
  if (blockIdx.x == 0 && blockIdx.y == 0) zpad[threadIdx.x] = 0.f;
}

// ---------------- fused final GEMM + dvec + VN-leakyrelu + partial n-sum ----
// n-split tile: 64 o x 32 n (NT=32 -> grid 1536 = 6 blocks/CU = 24 waves/CU,
// double R14's 12 -> barrier vmcnt drain hidden by other blocks' compute).
// Unlike R7's o-split, only the tiny W panel is duplicated (L2-resident);
// X loads and dv are per-n, distributed not duplicated. Async-DMA staging
// (global_load_lds w16), pointer-ternary on the K-tail (never a divergent
// branch around the DMA intrinsic — R10-verified pattern).
__device__ __forceinline__ void gl2lds16(const float* g, float* l) {
  __builtin_amdgcn_global_load_lds(
      (const __attribute__((address_space(1))) unsigned int*)g,
      (__attribute__((address_space(3))) unsigned int*)l, 16, 0, 0);
}

__global__ __launch_bounds__(256) void final_fused_kernel(
    const float* __restrict__ xcat, const float* __restrict__ Wt,
    const float* __restrict__ Wd4, const float* __restrict__ zpad,
    float* __restrict__ part) {
  __shared__ float Ws[2][16][64];     // [buf][f][o_col]   8 KB
  __shared__ float Xs[2][3][16][32];  // [buf][c][f][n]   12 KB
  __shared__ float Wda[176];
  int b = blockIdx.z;
  int o0 = blockIdx.y * 64;
  int n0 = blockIdx.x * 32;
  int t = threadIdx.x;
  int tx = t & 7, ty = t >> 3;  // compute: n = n0+tx*4+j, o = {o0+ty, o0+ty+32}
  int wv = t >> 6, lane = t & 63;

  if (t < 176) Wda[t] = (t < CCAT) ? Wd4[t] : 0.f;

  float acc[3][2][4];  // [c][o_i][n_j]
  float dv[3][4];      // [c][n_j]
#pragma unroll
  for (int c = 0; c < 3; ++c) {
#pragma unroll
    for (int i = 0; i < 2; ++i)
#pragma unroll
      for (int j = 0; j < 4; ++j) acc[c][i][j] = 0.f;
#pragma unroll
    for (int j = 0; j < 4; ++j) dv[c][j] = 0.f;
  }

  const float* xb = xcat + (size_t)b * CCAT * 3 * NN;
  const int NTILE = 11;  // 176 = 11*16 padded K

  // 10 KB per tile = 10 x 1KB wave-calls; wave wv issues calls wv, wv+4, wv+8.
  // call 0..5 -> X half-planes (c = call/2, f-half = call&1): row = 32 floats
  //   = 128B = 8 lanes x 16B -> lane l covers f = half*8 + (l>>3), ncol (l&7)*4.
  // call 6..9 -> W quarter (4 f-rows x 64 o): row = 256B = 16 lanes x 16B ->
  //   lane l covers f = (call-6)*4 + (l>>4), ocol (l&15)*4.
  auto stage = [&](int tt, int buf) {
#pragma unroll 1
    for (int cl = wv; cl < 10; cl += 4) {
      if (cl < 6) {
        int ch = cl >> 1, half = cl & 1;
        int fl = half * 8 + (lane >> 3);
        int f = tt * 16 + fl;
        const float* srcp =
            (f < CCAT) ? xb + ((size_t)f * 3 + ch) * NN + n0 + ((lane & 7) << 2)
                       : zpad + ((lane & 7) << 2);
        gl2lds16(srcp, &Xs[buf][ch][fl][(lane & 7) << 2]);
      } else {
        int fl = (cl - 6) * 4 + (lane >> 4);
        int f = tt * 16 + fl;
        const float* srcp = Wt + (size_t)f * WTLD + o0 + ((lane & 15) << 2);
        gl2lds16(srcp, &Ws[buf][fl][(lane & 15) << 2]);
      }
    }
  };

  stage(0, 0);

#pragma unroll 1
  for (int tt = 0; tt < NTILE; ++tt) {
    int buf = tt & 1;
    __syncthreads();  // vmcnt(0)+barrier: tile tt landed; buf^1 consumers done
    if (tt + 1 < NTILE) stage(tt + 1, buf ^ 1);
#pragma unroll
    for (int f2 = 0; f2 < 16; ++f2) {
      float w0 = Ws[buf][f2][ty];
      float w1 = Ws[buf][f2][ty + 32];
      float wd = Wda[tt * 16 + f2];
#pragma unroll
      for (int c = 0; c < 3; ++c) {
        float4 x = *(const float4*)&Xs[buf][c][f2][tx << 2];
        float xa[4] = {x.x, x.y, x.z, x.w};
#pragma unroll
        for (int j = 0; j < 4; ++j) dv[c][j] += wd * xa[j];
#pragma unroll
        for (int j = 0; j < 4; ++j) {
          acc[c][0][j] += w0 * xa[j];
          acc[c][1][j] += w1 * xa[j];
        }
      }
    }
  }

  float s[3][2];
#pragma unroll
  for (int c = 0; c < 3; ++c)
#pragma unroll
    for (int i = 0; i < 2; ++i) s[c][i] = 0.f;
#pragma unroll
  for (int i = 0; i < 2; ++i) {
#pragma unroll
    for (int j = 0; j < 4; ++j) {
      float d0 = dv[0][j], d1 = dv[1][j], d2 = dv[2][j];
      float p0 = acc[0][i][j], p1 = acc[1][i][j], p2 = acc[2][i][j];
      float dot = p0 * d0 + p1 * d1 + p2 * d2;
      float dsq = d0 * d0 + d1 * d1 + d2 * d2;
      float g = (dot >= 0.f) ? 0.f : 0.8f * dot / (dsq + 1e-6f);
      s[0][i] += p0 - g * d0;
      s[1][i] += p1 - g * d1;
      s[2][i] += p2 - g * d2;
    }
  }

  // n-reduce across the 8 tx lanes (low 3 bits of t)
#pragma unroll
  for (int off = 1; off < 8; off <<= 1) {
#pragma unroll
    for (int c = 0; c < 3; ++c)
#pragma unroll
      for (int i = 0; i < 2; ++i) s[c][i] += __shfl_xor(s[c][i], off, 64);
  }
  if (tx == 0) {
#pragma unroll
    for (int i = 0; i < 2; ++i) {
      int o = o0 + ty + i * 32;
      if (o < 341) {
#pragma unroll
        for (int c = 0; c < 3; ++c)
          part[(((size_t)b * 341 + o) * 3 + c) * NT + blockIdx.x] = s[c][i];
      }
    }
  }
}

__global__ void final_reduce_kernel(const float* __restrict__ part,
                                    float* __restrict__ out) {
  int t = blockIdx.x * 256 + threadIdx.x;
  if (t >= BB * 341 * 3) return;
  const float* p = part + (size_t)t * NT;
  float s = 0.f;
#pragma unroll
  for (int nt = 0; nt < NT; ++nt) s += p[nt];
  out[t] = s * (1.f / 1024.f);
}

extern "C" void kernel_launch(void* const* d_in, const int* in_sizes, int n_in,
                              void* d_out, int out_size, void* d_ws,
                              size_t ws_size, hipStream_t stream) {
  (void)in_sizes; (void)n_in; (void)out_size; (void)ws_size;
  const float* x = (const float*)d_in[0];
  const float* Wf[5] = {(const float*)d_in[1], (const float*)d_in[3],
                        (const float*)d_in[5], (const float*)d_in[7],
                        (const float*)d_in[9]};
  const float* Wd[5] = {(const float*)d_in[2], (const float*)d_in[4],
                        (const float*)d_in[6], (const float*)d_in[8],
                        (const float*)d_in[10]};

  float* ws = (float*)d_ws;
  float* dist = ws;
  float* part = ws;  // 8*341*3*32 = 261,888 floats < 262,144
  float* Wt = ws + 262144;
  float* zpad = Wt + 176 * WTLD;
  size_t off = (size_t)BB * NN * NN;
  int* idx = (int*)(ws + off);
  off += (size_t)BB * NN * KK;
  float* xcat = ws + off;

  struct LayerCfg { int D, Co, inoff, ooff, nsplit; };
  const LayerCfg L[4] = {
      {1, 21, 0, 0, 4},
      {21, 21, 0, 21, 4},
      {21, 42, 21, 42, 2},
      {42, 85, 42, 84, 1},
  };

  for (int l = 0; l < 4; ++l) {
    const float* src = (l == 0) ? x : (xcat + (size_t)L[l].inoff * 3 * NN);
    int bs = (l == 0) ? 3 * NN : CCAT * 3 * NN;
    int D = L[l].D, Co = L[l].Co;

    if (l == 0) {
      knn3_kernel<<<dim3(NN / 4, BB), 256, 0, stream>>>(x, idx);
    } else {
      dim3 dg(8, 8, BB);
      if (D == 21)
        dist_tile_kernel<63><<<dg, 256, 0, stream>>>(src, bs, dist);
      else
        dist_tile_kernel<126><<<dg, 256, 0, stream>>>(src, bs, dist);
      topk_kernel<<<(BB * NN) / 4, 256, 0, stream>>>(dist, idx);
    }

    dim3 eg(BB * Co, L[l].nsplit);
    if (D == 1)
      edge_fused_kernel<1><<<eg, 256, 0, stream>>>(
          src, bs, Co, L[l].nsplit, Wf[l], Wd[l], idx, L[l].ooff, xcat);
    else if (D == 21)
      edge_fused_kernel<21><<<eg, 256, 0, stream>>>(
          src, bs, Co, L[l].nsplit, Wf[l], Wd[l], idx, L[l].ooff, xcat);
    else
      edge_fused_kernel<42><<<eg, 256, 0, stream>>>(
          src, bs, Co, L[l].nsplit, Wf[l], Wd[l], idx, L[l].ooff, xcat);
  }

  prep_kernel<<<dim3(2, 176), 256, 0, stream>>>(Wf[4], Wt, zpad);
  final_fused_kernel<<<dim3(NT, 6, BB), 256, 0, stream>>>(xcat, Wt, Wd[4],
                                                          zpad, part);
  final_reduce_kernel<<<(BB * 341 * 3 + 255) / 256, 256, 0, stream>>>(
      part, (float*)d_out);
}

// Round 16
// 394.120 us; speedup vs baseline: 1.0515x; 1.0515x over previous
//
#include <hip/hip_runtime.h>
#include <cstddef>

#define BB 8
#define NN 1024
#define KK 20
#define CCAT 169
#define NT 16   // n-tiles of 64 in final fused GEMM
#define WTLD 384  // padded row length of transposed Wf4

// ---------------- neg dist, full grid, F-templated, double-buffered ---------
// (layers 2-4; layer 1 uses the fused knn3 kernel below)
template <int F>
__global__ __launch_bounds__(256) void dist_tile_kernel(
    const float* __restrict__ src, int bs, float* __restrict__ dist) {
  __shared__ float As[2][8][128];
  __shared__ float Bs[2][8][128];
  int b = blockIdx.z;
  int n0 = blockIdx.y * 128;
  int m0 = blockIdx.x * 128;
  int t = threadIdx.x;
  int tx = t & 15, ty = t >> 4;
  const float* p = src + (size_t)b * bs;

  float acc[8][8];
  float xn[8], xm[8];
#pragma unroll
  for (int i = 0; i < 8; ++i) {
    xn[i] = 0.f;
    xm[i] = 0.f;
#pragma unroll
    for (int j = 0; j < 8; ++j) acc[i][j] = 0.f;
  }

  int fr = t >> 5;
  int cc = (t & 31) << 2;
  constexpr int T = (F + 7) / 8;

  float4 av = {0.f, 0.f, 0.f, 0.f}, bv = {0.f, 0.f, 0.f, 0.f};
  if (fr < F) {  // tile 0
    av = *(const float4*)(p + (size_t)fr * NN + n0 + cc);
    bv = *(const float4*)(p + (size_t)fr * NN + m0 + cc);
  }
  *(float4*)&As[0][fr][cc] = av;
  *(float4*)&Bs[0][fr][cc] = bv;

#pragma unroll 1
  for (int k = 0; k < T; ++k) {
    __syncthreads();  // tile k staged; buf^1 consumers (tile k-1) done
    if (k + 1 < T) {
      int f = (k + 1) * 8 + fr;
      av = make_float4(0.f, 0.f, 0.f, 0.f);
      bv = make_float4(0.f, 0.f, 0.f, 0.f);
      if (f < F) {
        av = *(const float4*)(p + (size_t)f * NN + n0 + cc);
        bv = *(const float4*)(p + (size_t)f * NN + m0 + cc);
      }
    }
    const float(*A)[128] = As[k & 1];
    const float(*B)[128] = Bs[k & 1];
#pragma unroll
    for (int f2 = 0; f2 < 8; ++f2) {
      float4 al = *(const float4*)&A[f2][ty << 2];
      float4 ah = *(const float4*)&A[f2][64 + (ty << 2)];
      float4 bl = *(const float4*)&B[f2][tx << 2];
      float4 bh = *(const float4*)&B[f2][64 + (tx << 2)];
      float a[8] = {al.x, al.y, al.z, al.w, ah.x, ah.y, ah.z, ah.w};
      float bb[8] = {bl.x, bl.y, bl.z, bl.w, bh.x, bh.y, bh.z, bh.w};
#pragma unroll
      for (int i = 0; i < 8; ++i) xn[i] += a[i] * a[i];
#pragma unroll
      for (int j = 0; j < 8; ++j) xm[j] += bb[j] * bb[j];
#pragma unroll
      for (int i = 0; i < 8; ++i)
#pragma unroll
        for (int j = 0; j < 8; ++j) acc[i][j] += a[i] * bb[j];
    }
    if (k + 1 < T) {
      *(float4*)&As[(k + 1) & 1][fr][cc] = av;  // vmcnt wait lands HERE
      *(float4*)&Bs[(k + 1) & 1][fr][cc] = bv;
    }
  }

#pragma unroll
  for (int i = 0; i < 8; ++i)
#pragma unroll
    for (int j = 0; j < 8; ++j) acc[i][j] = 2.f * acc[i][j] - xn[i] - xm[j];

#pragma unroll
  for (int i = 0; i < 8; ++i) {
    int n = n0 + ((i < 4) ? ((ty << 2) + i) : (64 + (ty << 2) + i - 4));
    float* dr = dist + (((size_t)b * NN + n) << 10);
    *(float4*)(dr + m0 + (tx << 2)) =
        make_float4(acc[i][0], acc[i][1], acc[i][2], acc[i][3]);
    *(float4*)(dr + m0 + 64 + (tx << 2)) =
        make_float4(acc[i][4], acc[i][5], acc[i][6], acc[i][7]);
  }
}

// ---------------- shared top-k core: sort 16 keys, LDS queue, tournament ----
// Keys: hi32 = order-preserving float->uint map, lo32 = (1023-m): ties break
// toward LOWER index (jax semantics); all keys unique.
__device__ __forceinline__ void topk_core(
    unsigned long long key[16], unsigned long long (*q)[64], int lane,
    int* out) {
  // bitonic sort, descending (compile-time indices -> stays in VGPRs)
#pragma unroll
  for (int size = 2; size <= 16; size <<= 1) {
#pragma unroll
    for (int stride = size >> 1; stride > 0; stride >>= 1) {
#pragma unroll
      for (int i = 0; i < 16; ++i) {
        int j = i ^ stride;
        if (j > i) {
          unsigned long long a = key[i], c = key[j];
          bool desc = ((i & size) == 0);
          bool sw = desc ? (a < c) : (a > c);
          key[i] = sw ? c : a;
          key[j] = sw ? a : c;
        }
      }
    }
  }

  // spill sorted tail (slots 1..15) + sentinel; head stays in register
#pragma unroll
  for (int s = 1; s < 16; ++s) q[s - 1][lane] = key[s];
  q[15][lane] = 0ull;  // sentinel: below every real key, can't tie

  unsigned long long head = key[0];
  int ptr = 0;
  for (int r = 0; r < KK; ++r) {
    unsigned hv = (unsigned)(head >> 32);
    unsigned v = hv;
#pragma unroll
    for (int off = 32; off > 0; off >>= 1) {
      unsigned o = __shfl_xor(v, off, 64);
      v = (o > v) ? o : v;
    }
    unsigned long long tie = __ballot(hv == v);
    unsigned il;
    if (tie & (tie - 1)) {  // >=2 lanes tie in value: reduce low word
      unsigned c = (hv == v) ? (unsigned)head : 0u;
#pragma unroll
      for (int off = 32; off > 0; off >>= 1) {
        unsigned o = __shfl_xor(c, off, 64);
        c = (o > c) ? o : c;
      }
      il = c;
    } else {
      int wl = __builtin_ctzll(tie);
      il = __shfl((unsigned)head, wl, 64);
    }
    if (lane == 0) out[r] = (NN - 1) - (int)il;
    if (hv == v && (unsigned)head == il) {  // unique winner pops from LDS
      head = q[ptr][lane];
      ++ptr;
    }
  }
}

__device__ __forceinline__ unsigned long long mk_key(float val, int m) {
  unsigned u = __float_as_uint(val);
  u = (u & 0x80000000u) ? ~u : (u | 0x80000000u);
  return ((unsigned long long)u << 32) | (unsigned)(NN - 1 - m);
}

// ---------------- top-k from the dist matrix (layers 2-4) ----------------
__global__ __launch_bounds__(256) void topk_kernel(
    const float* __restrict__ dist, int* __restrict__ idx_out) {
  __shared__ unsigned long long q[4][16][64];  // 32 KB
  int wave = threadIdx.x >> 6;
  int lane = threadIdx.x & 63;
  int row = blockIdx.x * 4 + wave;
  const float* d = dist + ((size_t)row << 10);

  unsigned long long key[16];
  {
    const float4* dp = (const float4*)(d + (lane << 4));
#pragma unroll
    for (int qd = 0; qd < 4; ++qd) {
      float4 v4 = dp[qd];
      float vv[4] = {v4.x, v4.y, v4.z, v4.w};
#pragma unroll
      for (int e = 0; e < 4; ++e)
        key[(qd << 2) + e] = mk_key(vv[e], (lane << 4) + (qd << 2) + e);
    }
  }
  topk_core(key, q[wave], lane, idx_out + row * KK);
}

// ---------------- fused dist+topk for layer 1 (F=3): x fits in LDS ---------
// No 33.5 MB dist round-trip, one launch instead of two. Per-lane ownership
// strided (m = lane + s*64): conflict-free b32 LDS reads. Key encodes m
// explicitly -> selection identical regardless of ownership layout.
__global__ __launch_bounds__(256) void knn3_kernel(
    const float* __restrict__ src, int* __restrict__ idx_out) {
  __shared__ float xl[3 * NN];                 // 12 KB
  __shared__ unsigned long long q[4][16][64];  // 32 KB
  int b = blockIdx.y;
  int t = threadIdx.x;
  int wave = t >> 6;
  int lane = t & 63;
  int n = blockIdx.x * 4 + wave;  // row within batch
  const float* sb = src + (size_t)b * 3 * NN;

#pragma unroll
  for (int r = 0; r < 3; ++r)
    ((float4*)xl)[t + 256 * r] = ((const float4*)sb)[t + 256 * r];
  __syncthreads();

  float xn0 = xl[n], xn1 = xl[NN + n], xn2 = xl[2 * NN + n];
  float xnn = xn0 * xn0 + xn1 * xn1 + xn2 * xn2;

  unsigned long long key[16];
#pragma unroll
  for (int s = 0; s < 16; ++s) {
    int m = lane + (s << 6);
    float xm0 = xl[m], xm1 = xl[NN + m], xm2 = xl[2 * NN + m];
    float dot = xn0 * xm0 + xn1 * xm1 + xn2 * xm2;
    float xmn = xm0 * xm0 + xm1 * xm1 + xm2 * xm2;
    key[s] = mk_key(2.f * dot - xnn - xmn, m);
  }
  topk_core(key, q[wave], lane, idx_out + ((size_t)b * NN + n) * KK);
}

// ---------------- fused transform + edge combine + mean over k --------------
// Packed LDS: UA[n]={uf0,ud0,uf1,ud1}, UB[n]={uf2,ud2} (same for V) ->
// 2 LDS reads per gather instead of 3. Values & expression order identical
// to the float2x3 layout -> bitwise-identical xcat.
template <int DD>
__global__ __launch_bounds__(256) void edge_fused_kernel(
    const float* __restrict__ src, int bs, int Co, int nsplit,
    const float* __restrict__ Wf, const float* __restrict__ Wd,
    const int* __restrict__ idx, int ooff, float* __restrict__ xcat) {
  __shared__ float4 UA[NN];   // 16 KB
  __shared__ float2 UB2[NN];  // 8 KB
  __shared__ float4 VA[NN];   // 16 KB
  __shared__ float2 VB2[NN];  // 8 KB
  __shared__ float4 Wlds[48];
  int bo = blockIdx.x;
  int b = bo / Co, o = bo % Co;
  int t = threadIdx.x;

  if (t < DD) {
    float wfa = Wf[o * 2 * DD + t];
    float wfb = Wf[o * 2 * DD + DD + t] - wfa;
    float wda = Wd[o * 2 * DD + t];
    float wdb = Wd[o * 2 * DD + DD + t] - wda;
    Wlds[t] = make_float4(wfa, wfb, wda, wdb);
  }
  __syncthreads();

  const float* sb = src + (size_t)b * bs;
  {
    int c0 = t << 2;
    float uf[3][4], vf[3][4], ud[3][4], vd[3][4];
#pragma unroll
    for (int r = 0; r < 3; ++r)
#pragma unroll
      for (int e = 0; e < 4; ++e) {
        uf[r][e] = 0.f; vf[r][e] = 0.f; ud[r][e] = 0.f; vd[r][e] = 0.f;
      }
#pragma unroll 2
    for (int i = 0; i < DD; ++i) {
      const float* row = sb + (size_t)i * 3 * NN + c0;
      float4 s0 = *(const float4*)(row);
      float4 s1 = *(const float4*)(row + 1024);
      float4 s2 = *(const float4*)(row + 2048);
      float se[3][4] = {{s0.x, s0.y, s0.z, s0.w},
                        {s1.x, s1.y, s1.z, s1.w},
                        {s2.x, s2.y, s2.z, s2.w}};
      float4 w = Wlds[i];
#pragma unroll
      for (int r = 0; r < 3; ++r)
#pragma unroll
        for (int e = 0; e < 4; ++e) {
          uf[r][e] += w.x * se[r][e];
          vf[r][e] += w.y * se[r][e];
          ud[r][e] += w.z * se[r][e];
          vd[r][e] += w.w * se[r][e];
        }
    }
#pragma unroll
    for (int e = 0; e < 4; ++e) {
      int n = (t << 2) + e;
      UA[n] = make_float4(uf[0][e], ud[0][e], uf[1][e], ud[1][e]);
      UB2[n] = make_float2(uf[2][e], ud[2][e]);
      VA[n] = make_float4(vf[0][e], vd[0][e], vf[1][e], vd[1][e]);
      VB2[n] = make_float2(vf[2][e], vd[2][e]);
    }
  }
  __syncthreads();

  const float inv_k = 1.f / KK;
  int cnt = NN / nsplit;
  int nbase = blockIdx.y * cnt;
  for (int n = nbase + t; n < nbase + cnt; n += 256) {
    float4 va = VA[n];
    float2 vb = VB2[n];
    const int4* ip = (const int4*)(idx + (b * NN + n) * KK);
    float a0 = 0.f, a1 = 0.f, a2 = 0.f;
#pragma unroll
    for (int qq = 0; qq < 5; ++qq) {
      int4 iv = ip[qq];
      int nbs[4] = {iv.x, iv.y, iv.z, iv.w};
#pragma unroll
      for (int jj = 0; jj < 4; ++jj) {
        int nb = nbs[jj];
        float4 ua = UA[nb];
        float2 ub = UB2[nb];
        float pf0 = ua.x + va.x, pd0 = ua.y + va.y;
        float pf1 = ua.z + va.z, pd1 = ua.w + va.w;
        float pf2 = ub.x + vb.x, pd2 = ub.y + vb.y;
        float dot = pf0 * pd0 + pf1 * pd1 + pf2 * pd2;
        float dsq = pd0 * pd0 + pd1 * pd1 + pd2 * pd2;
        float g = (dot >= 0.f) ? 0.f : 0.8f * dot / (dsq + 1e-6f);
        a0 += pf0 - g * pd0;
        a1 += pf1 - g * pd1;
        a2 += pf2 - g * pd2;
      }
    }
    size_t ob = (size_t)b * CCAT * 3 * NN + (size_t)(ooff + o) * 3 * NN + n;
    xcat[ob] = a0 * inv_k;
    xcat[ob + NN] = a1 * inv_k;
    xcat[ob + 2 * NN] = a2 * inv_k;
  }
}

// ---------------- prep: transpose Wf4 -> Wt[176][384] (zero-padded), zero pad
__global__ __launch_bounds__(256) void prep_kernel(
    const float* __restrict__ Wf4, float* __restrict__ Wt,
    float* __restrict__ zpad) {
  int o = blockIdx.x * 256 + threadIdx.x;  // 0..511
  int f = blockIdx.y;                      // 0..175
  if (o < WTLD)
    Wt[(size_t)f * WTLD + o] = (f < CCAT && o < 341) ? Wf4[o * CCAT + f] : 0.f;
  if (blockIdx.x == 0 && blockIdx.y == 0) zpad[threadIdx.x] = 0.f;
}

// ---------------- fused final GEMM + dvec + VN-leakyrelu + partial n-sum ----
// Async-DMA staging (global_load_lds w16): staged data never touches VGPRs.
// Double-buffered LDS, one barrier per tile. 64o x 64n, NT=16 — empirically
// optimal: o-split (R7), reg-staging (R1/R9), 512-thr (R3-R5), n-split (R15)
// all regressed. ~70 µs is this kernel's measured floor.
__device__ __forceinline__ void gl2lds16(const float* g, float* l) {
  __builtin_amdgcn_global_load_lds(
      (const __attribute__((address_space(1))) unsigned int*)g,
      (__attribute__((address_space(3))) unsigned int*)l, 16, 0, 0);
}

__global__ __launch_bounds__(256) void final_fused_kernel(
    const float* __restrict__ xcat, const float* __restrict__ Wt,
    const float* __restrict__ Wd4, const float* __restrict__ zpad,
    float* __restrict__ part) {
  __shared__ float Ws[2][16][64];     // [buf][f][o_col]   8.2 KB
  __shared__ float Xs[2][3][16][64];  // [buf][c][f][n]   24.6 KB
  __shared__ float Wda[176];
  int b = blockIdx.z;
  int o0 = blockIdx.y * 64;
  int n0 = blockIdx.x * 64;
  int t = threadIdx.x;
  int tx = t & 15, ty = t >> 4;

  if (t < 176) Wda[t] = (t < CCAT) ? Wd4[t] : 0.f;

  float acc[3][4][4];  // [c][o_i][n_j]
  float dv[3][4];      // [c][n_j]
#pragma unroll
  for (int c = 0; c < 3; ++c) {
#pragma unroll
    for (int i = 0; i < 4; ++i)
#pragma unroll
      for (int j = 0; j < 4; ++j) acc[c][i][j] = 0.f;
#pragma unroll
    for (int j = 0; j < 4; ++j) dv[c][j] = 0.f;
  }

  const float* xb = xcat + (size_t)b * CCAT * 3 * NN;
  const int NTILE = 11;  // 176 = 11*16 padded K

  {
    const float* wsrc = Wt + (size_t)ty * WTLD + o0 + (tx << 2);
    gl2lds16(wsrc, &Ws[0][ty][tx << 2]);
#pragma unroll
    for (int c = 0; c < 3; ++c) {
      const float* xsrc = xb + ((size_t)ty * 3 + c) * NN + n0 + (tx << 2);
      gl2lds16(xsrc, &Xs[0][c][ty][tx << 2]);
    }
  }

#pragma unroll 1
  for (int tt = 0; tt < NTILE; ++tt) {
    int buf = tt & 1;
    __syncthreads();  // vmcnt(0)+barrier: tile tt landed; buf^1 consumers done
    if (tt + 1 < NTILE) {
      int f = (tt + 1) * 16 + ty;
      const float* wsrc = Wt + (size_t)f * WTLD + o0 + (tx << 2);
      gl2lds16(wsrc, &Ws[buf ^ 1][ty][tx << 2]);
#pragma unroll
      for (int c = 0; c < 3; ++c) {
        const float* xsrc = (f < CCAT)
                                ? xb + ((size_t)f * 3 + c) * NN + n0 + (tx << 2)
                                : zpad + (tx << 2);
        gl2lds16(xsrc, &Xs[buf ^ 1][c][ty][tx << 2]);
      }
    }
#pragma unroll
    for (int f2 = 0; f2 < 16; ++f2) {
      float4 w = *(const float4*)&Ws[buf][f2][ty << 2];
      float wa[4] = {w.x, w.y, w.z, w.w};
      float wd = Wda[tt * 16 + f2];
#pragma unroll
      for (int c = 0; c < 3; ++c) {
        float4 x = *(const float4*)&Xs[buf][c][f2][tx << 2];
        float xa[4] = {x.x, x.y, x.z, x.w};
#pragma unroll
        for (int j = 0; j < 4; ++j) dv[c][j] += wd * xa[j];
#pragma unroll
        for (int i = 0; i < 4; ++i)
#pragma unroll
          for (int j = 0; j < 4; ++j) acc[c][i][j] += wa[i] * xa[j];
      }
    }
  }

  float s[3][4];
#pragma unroll
  for (int c = 0; c < 3; ++c)
#pragma unroll
    for (int i = 0; i < 4; ++i) s[c][i] = 0.f;
#pragma unroll
  for (int i = 0; i < 4; ++i) {
#pragma unroll
    for (int j = 0; j < 4; ++j) {
      float d0 = dv[0][j], d1 = dv[1][j], d2 = dv[2][j];
      float p0 = acc[0][i][j], p1 = acc[1][i][j], p2 = acc[2][i][j];
      float dot = p0 * d0 + p1 * d1 + p2 * d2;
      float dsq = d0 * d0 + d1 * d1 + d2 * d2;
      float g = (dot >= 0.f) ? 0.f : 0.8f * dot / (dsq + 1e-6f);
      s[0][i] += p0 - g * d0;
      s[1][i] += p1 - g * d1;
      s[2][i] += p2 - g * d2;
    }
  }

#pragma unroll
  for (int off = 1; off < 16; off <<= 1) {
#pragma unroll
    for (int c = 0; c < 3; ++c)
#pragma unroll
      for (int i = 0; i < 4; ++i) s[c][i] += __shfl_xor(s[c][i], off, 64);
  }
  if (tx == 0) {
#pragma unroll
    for (int i = 0; i < 4; ++i) {
      int o = o0 + (ty << 2) + i;
      if (o < 341) {
#pragma unroll
        for (int c = 0; c < 3; ++c)
          part[(((size_t)b * 341 + o) * 3 + c) * NT + blockIdx.x] = s[c][i];
      }
    }
  }
}

__global__ void final_reduce_kernel(const float* __restrict__ part,
                                    float* __restrict__ out) {
  int t = blockIdx.x * 256 + threadIdx.x;
  if (t >= BB * 341 * 3) return;
  const float* p = part + (size_t)t * NT;
  float s = 0.f;
#pragma unroll
  for (int nt = 0; nt < NT; ++nt) s += p[nt];
  out[t] = s * (1.f / 1024.f);
}

extern "C" void kernel_launch(void* const* d_in, const int* in_sizes, int n_in,
                              void* d_out, int out_size, void* d_ws,
                              size_t ws_size, hipStream_t stream) {
  (void)in_sizes; (void)n_in; (void)out_size; (void)ws_size;
  const float* x = (const float*)d_in[0];
  const float* Wf[5] = {(const float*)d_in[1], (const float*)d_in[3],
                        (const float*)d_in[5], (const float*)d_in[7],
                        (const float*)d_in[9]};
  const float* Wd[5] = {(const float*)d_in[2], (const float*)d_in[4],
                        (const float*)d_in[6], (const float*)d_in[8],
                        (const float*)d_in[10]};

  float* ws = (float*)d_ws;
  float* dist = ws;
  float* part = ws;
  float* Wt = ws + 262144;
  float* zpad = Wt + 176 * WTLD;
  size_t off = (size_t)BB * NN * NN;
  int* idx = (int*)(ws + off);
  off += (size_t)BB * NN * KK;
  float* xcat = ws + off;

  struct LayerCfg { int D, Co, inoff, ooff, nsplit; };
  const LayerCfg L[4] = {
      {1, 21, 0, 0, 4},
      {21, 21, 0, 21, 4},
      {21, 42, 21, 42, 2},
      {42, 85, 42, 84, 1},
  };

  for (int l = 0; l < 4; ++l) {
    const float* src = (l == 0) ? x : (xcat + (size_t)L[l].inoff * 3 * NN);
    int bs = (l == 0) ? 3 * NN : CCAT * 3 * NN;
    int D = L[l].D, Co = L[l].Co;

    if (l == 0) {
      knn3_kernel<<<dim3(NN / 4, BB), 256, 0, stream>>>(x, idx);
    } else {
      dim3 dg(8, 8, BB);
      if (D == 21)
        dist_tile_kernel<63><<<dg, 256, 0, stream>>>(src, bs, dist);
      else
        dist_tile_kernel<126><<<dg, 256, 0, stream>>>(src, bs, dist);
      topk_kernel<<<(BB * NN) / 4, 256, 0, stream>>>(dist, idx);
    }

    dim3 eg(BB * Co, L[l].nsplit);
    if (D == 1)
      edge_fused_kernel<1><<<eg, 256, 0, stream>>>(
          src, bs, Co, L[l].nsplit, Wf[l], Wd[l], idx, L[l].ooff, xcat);
    else if (D == 21)
      edge_fused_kernel<21><<<eg, 256, 0, stream>>>(
          src, bs, Co, L[l].nsplit, Wf[l], Wd[l], idx, L[l].ooff, xcat);
    else
      edge_fused_kernel<42><<<eg, 256, 0, stream>>>(
          src, bs, Co, L[l].nsplit, Wf[l], Wd[l], idx, L[l].ooff, xcat);
  }

  prep_kernel<<<dim3(2, 176), 256, 0, stream>>>(Wf[4], Wt, zpad);
  final_fused_kernel<<<dim3(NT, 6, BB), 256, 0, stream>>>(xcat, Wt, Wd[4],
                                                          zpad, part);
  final_reduce_kernel<<<(BB * 341 * 3 + 255) / 256, 256, 0, stream>>>(
      part, (float*)d_out);
}